// Round 1
// baseline (3868.298 us; speedup 1.0000x reference)
//
#include <hip/hip_runtime.h>
#include <math.h>

#define N_NODES 50000
#define N_EDGES 800000
#define DIM 64
#define N_LAYERS 5

#define MLP_BLOCK 128
#define MLP_ROWS 128
#define HSTRIDE 65   // pad: bank = (r*65+k)%32 = (r+k)%32 -> conflict-free across lanes

__global__ void zero_pooled(float* pooled) {
    int t = threadIdx.x;
    if (t < N_LAYERS * DIM) pooled[t] = 0.f;
}

__global__ void copy_kernel(const float* __restrict__ s, float* __restrict__ d, int n4) {
    int i = blockIdx.x * blockDim.x + threadIdx.x;
    if (i < n4) ((float4*)d)[i] = ((const float4*)s)[i];
}

// one thread per (edge, 4-float group): wave = 4 edges, coalesced 256B gather per edge
__global__ __launch_bounds__(256) void scatter_kernel(const float* __restrict__ h,
                                                      const int* __restrict__ src,
                                                      const int* __restrict__ dst,
                                                      float* __restrict__ agg) {
    int t = blockIdx.x * 256 + threadIdx.x;
    int e = t >> 4;
    if (e >= N_EDGES) return;
    int g = (t & 15) << 2;
    int s = src[e];
    int d = dst[e];
    float4 v = *(const float4*)(h + (size_t)s * DIM + g);
    float* a = agg + (size_t)d * DIM + g;
    atomicAdd(a + 0, v.x);
    atomicAdd(a + 1, v.y);
    atomicAdd(a + 2, v.z);
    atomicAdd(a + 3, v.w);
}

// lane = node row. Row lives in LDS (private per lane, stride 65). W accesses are
// wave-uniform -> compiler scalarizes to s_load; FMAs take SGPR operand. FMA-bound.
__global__ __launch_bounds__(MLP_BLOCK) void mlp_kernel(const float* __restrict__ agg,
                                                        const float* __restrict__ W,   // [3][64][64] this layer
                                                        float* __restrict__ h_out,
                                                        float* __restrict__ agg_next,
                                                        float* __restrict__ pooled) {  // [64] this layer
    __shared__ float H[MLP_ROWS * HSTRIDE];
    const int tid  = threadIdx.x;
    const int row0 = blockIdx.x * MLP_ROWS;

    // coalesced global -> LDS fill: 128 rows * 64 cols = 2048 float4
    #pragma unroll
    for (int i = 0; i < 16; ++i) {
        int f4 = tid + i * MLP_BLOCK;
        int r  = f4 >> 4;
        int c  = (f4 & 15) << 2;
        int grow = row0 + r;
        float4 v = make_float4(0.f, 0.f, 0.f, 0.f);
        if (grow < N_NODES) v = *(const float4*)(agg + (size_t)grow * DIM + c);
        *(float4*)&H[r * HSTRIDE + c] = v;
    }
    __syncthreads();

    float* hrow = &H[tid * HSTRIDE];
    for (int p = 0; p < 3; ++p) {
        const float* Wp = W + p * DIM * DIM;
        float4 acc[16];
        #pragma unroll
        for (int i = 0; i < 16; ++i) acc[i] = make_float4(0.f, 0.f, 0.f, 0.f);
        for (int k = 0; k < DIM; ++k) {
            float hk = hrow[k];                 // ds_read_b32, bank (tid+k)%32
            const float* wr = Wp + k * DIM;     // wave-uniform
            #pragma unroll
            for (int c4 = 0; c4 < 16; ++c4) {
                float4 w = *(const float4*)(wr + c4 * 4);   // uniform -> s_load
                acc[c4].x = fmaf(hk, w.x, acc[c4].x);
                acc[c4].y = fmaf(hk, w.y, acc[c4].y);
                acc[c4].z = fmaf(hk, w.z, acc[c4].z);
                acc[c4].w = fmaf(hk, w.w, acc[c4].w);
            }
        }
        // relu + write own row back (no cross-thread readers until the sync below)
        #pragma unroll
        for (int c4 = 0; c4 < 16; ++c4) {
            float4 v;
            v.x = fmaxf(acc[c4].x, 0.f);
            v.y = fmaxf(acc[c4].y, 0.f);
            v.z = fmaxf(acc[c4].z, 0.f);
            v.w = fmaxf(acc[c4].w, 0.f);
            *(float4*)&hrow[c4 * 4] = v;
        }
    }
    __syncthreads();

    // coalesced LDS -> global stores (h for next scatter, agg_next = h init)
    #pragma unroll
    for (int i = 0; i < 16; ++i) {
        int f4 = tid + i * MLP_BLOCK;
        int r  = f4 >> 4;
        int c  = (f4 & 15) << 2;
        int grow = row0 + r;
        if (grow < N_NODES) {
            float4 v = *(const float4*)&H[r * HSTRIDE + c];
            *(float4*)(h_out    + (size_t)grow * DIM + c) = v;
            *(float4*)(agg_next + (size_t)grow * DIM + c) = v;
        }
    }

    // per-block column sums for the mean pool (invalid rows are zero)
    int c    = tid & 63;
    int half = tid >> 6;
    float s = 0.f;
    #pragma unroll 8
    for (int j = 0; j < 64; ++j) {
        int r = half * 64 + j;
        s += H[r * HSTRIDE + c];
    }
    atomicAdd(&pooled[c], s);
}

__global__ void finalize_kernel(const float* __restrict__ pooled,
                                const float* __restrict__ Wl,
                                float* __restrict__ out) {
    int c = threadIdx.x;  // 64 threads
    float s = 0.f;
    #pragma unroll
    for (int l = 0; l < N_LAYERS; ++l)
        s += pooled[l * DIM + c] * Wl[l * DIM + c];
    #pragma unroll
    for (int off = 32; off > 0; off >>= 1)
        s += __shfl_down(s, off, 64);
    if (c == 0) {
        float logit = s / (float)N_NODES;
        out[0] = 1.f / (1.f + expf(-logit));
    }
}

extern "C" void kernel_launch(void* const* d_in, const int* in_sizes, int n_in,
                              void* d_out, int out_size, void* d_ws, size_t ws_size,
                              hipStream_t stream) {
    const float* x   = (const float*)d_in[0];
    const float* W   = (const float*)d_in[1];
    const float* Wl  = (const float*)d_in[2];
    const int*   src = (const int*)d_in[3];
    const int*   dst = (const int*)d_in[4];
    float* out = (float*)d_out;

    char* ws = (char*)d_ws;
    const size_t nodeBytes = (size_t)N_NODES * DIM * sizeof(float);  // 12.8 MB
    float* aggA   = (float*)(ws);
    float* aggB   = (float*)(ws + nodeBytes);
    float* h      = (float*)(ws + 2 * nodeBytes);
    float* pooled = (float*)(ws + 3 * nodeBytes);  // 5*64 floats

    zero_pooled<<<1, 320, 0, stream>>>(pooled);
    copy_kernel<<<(N_NODES * DIM / 4 + 255) / 256, 256, 0, stream>>>(x, aggA, N_NODES * DIM / 4);

    const float* hcur = x;
    float* agg  = aggA;
    float* aggN = aggB;
    for (int l = 0; l < N_LAYERS; ++l) {
        scatter_kernel<<<(N_EDGES * 16 + 255) / 256, 256, 0, stream>>>(hcur, src, dst, agg);
        mlp_kernel<<<(N_NODES + MLP_ROWS - 1) / MLP_ROWS, MLP_BLOCK, 0, stream>>>(
            agg, W + (size_t)l * 3 * DIM * DIM, h, aggN, pooled + l * DIM);
        hcur = h;
        float* t = agg; agg = aggN; aggN = t;
    }
    finalize_kernel<<<1, 64, 0, stream>>>(pooled, Wl, out);
}

// Round 2
// 811.980 us; speedup vs baseline: 4.7640x; 4.7640x over previous
//
#include <hip/hip_runtime.h>
#include <math.h>

#define N_NODES 50000
#define N_EDGES 800000
#define DIM 64
#define N_LAYERS 5

#define MLP_BLOCK 128
#define MLP_ROWS 128
#define HSTRIDE 65   // pad: bank = (r*65+k)%32 = (r+k)%32 -> conflict-free across lanes

// ---------------- CSR build (per call; ws is re-poisoned every launch) ----------------

__global__ __launch_bounds__(256) void hist_kernel(const int* __restrict__ dst,
                                                   int* __restrict__ counts) {
    int e = blockIdx.x * 256 + threadIdx.x;
    if (e < N_EDGES) atomicAdd(&counts[dst[e]], 1);
}

#define SCAN_T 1024
#define CHUNK ((N_NODES + SCAN_T - 1) / SCAN_T)   // 49

__global__ __launch_bounds__(SCAN_T) void scan_kernel(const int* __restrict__ counts,
                                                      int* __restrict__ rowptr) {
    __shared__ int sums[SCAN_T];
    int tid = threadIdx.x;
    int lo = tid * CHUNK;
    int hi = min(lo + CHUNK, N_NODES);
    int s = 0;
    for (int i = lo; i < hi; ++i) s += counts[i];
    sums[tid] = s;
    __syncthreads();
    // Hillis-Steele inclusive scan over 1024 thread totals
    for (int off = 1; off < SCAN_T; off <<= 1) {
        int v = (tid >= off) ? sums[tid - off] : 0;
        __syncthreads();
        sums[tid] += v;
        __syncthreads();
    }
    int run = (tid > 0) ? sums[tid - 1] : 0;
    for (int i = lo; i < hi; ++i) { rowptr[i] = run; run += counts[i]; }
    if (tid == SCAN_T - 1) rowptr[N_NODES] = run;   // == N_EDGES
}

__global__ __launch_bounds__(256) void fill_kernel(const int* __restrict__ src,
                                                   const int* __restrict__ dst,
                                                   const int* __restrict__ rowptr,
                                                   int* __restrict__ cursor,
                                                   int* __restrict__ csr_src) {
    int e = blockIdx.x * 256 + threadIdx.x;
    if (e >= N_EDGES) return;
    int d = dst[e];
    int pos = atomicAdd(&cursor[d], 1);
    csr_src[rowptr[d] + pos] = src[e];
}

// ---------------- aggregation: gather, no atomics ----------------
// 16 threads per node, one float4 slice each; csr_src read broadcasts within the 16-group.
__global__ __launch_bounds__(256) void gather_kernel(const float* __restrict__ h,
                                                     const int* __restrict__ rowptr,
                                                     const int* __restrict__ csr_src,
                                                     float* __restrict__ agg) {
    int t = blockIdx.x * 256 + threadIdx.x;
    int node = t >> 4;
    if (node >= N_NODES) return;
    int g = (t & 15) << 2;
    float4 acc = *(const float4*)(h + (size_t)node * DIM + g);   // self term (eps=0)
    int e0 = rowptr[node], e1 = rowptr[node + 1];
    for (int e = e0; e < e1; ++e) {
        int s = csr_src[e];
        float4 v = *(const float4*)(h + (size_t)s * DIM + g);
        acc.x += v.x; acc.y += v.y; acc.z += v.z; acc.w += v.w;
    }
    *(float4*)(agg + (size_t)node * DIM + g) = acc;
}

// ---------------- MLP (unchanged structure from R0) ----------------
__global__ __launch_bounds__(MLP_BLOCK) void mlp_kernel(const float* __restrict__ agg,
                                                        const float* __restrict__ W,   // [3][64][64]
                                                        float* __restrict__ h_out,
                                                        float* __restrict__ pooled) {  // [64]
    __shared__ float H[MLP_ROWS * HSTRIDE];
    const int tid  = threadIdx.x;
    const int row0 = blockIdx.x * MLP_ROWS;

    #pragma unroll
    for (int i = 0; i < 16; ++i) {
        int f4 = tid + i * MLP_BLOCK;
        int r  = f4 >> 4;
        int c  = (f4 & 15) << 2;
        int grow = row0 + r;
        float4 v = make_float4(0.f, 0.f, 0.f, 0.f);
        if (grow < N_NODES) v = *(const float4*)(agg + (size_t)grow * DIM + c);
        *(float4*)&H[r * HSTRIDE + c] = v;
    }
    __syncthreads();

    float* hrow = &H[tid * HSTRIDE];
    for (int p = 0; p < 3; ++p) {
        const float* Wp = W + p * DIM * DIM;
        float4 acc[16];
        #pragma unroll
        for (int i = 0; i < 16; ++i) acc[i] = make_float4(0.f, 0.f, 0.f, 0.f);
        for (int k = 0; k < DIM; ++k) {
            float hk = hrow[k];
            const float* wr = Wp + k * DIM;     // wave-uniform -> s_load
            #pragma unroll
            for (int c4 = 0; c4 < 16; ++c4) {
                float4 w = *(const float4*)(wr + c4 * 4);
                acc[c4].x = fmaf(hk, w.x, acc[c4].x);
                acc[c4].y = fmaf(hk, w.y, acc[c4].y);
                acc[c4].z = fmaf(hk, w.z, acc[c4].z);
                acc[c4].w = fmaf(hk, w.w, acc[c4].w);
            }
        }
        #pragma unroll
        for (int c4 = 0; c4 < 16; ++c4) {
            float4 v;
            v.x = fmaxf(acc[c4].x, 0.f);
            v.y = fmaxf(acc[c4].y, 0.f);
            v.z = fmaxf(acc[c4].z, 0.f);
            v.w = fmaxf(acc[c4].w, 0.f);
            *(float4*)&hrow[c4 * 4] = v;
        }
    }
    __syncthreads();

    #pragma unroll
    for (int i = 0; i < 16; ++i) {
        int f4 = tid + i * MLP_BLOCK;
        int r  = f4 >> 4;
        int c  = (f4 & 15) << 2;
        int grow = row0 + r;
        if (grow < N_NODES)
            *(float4*)(h_out + (size_t)grow * DIM + c) = *(const float4*)&H[r * HSTRIDE + c];
    }

    // per-block column sums for the global mean pool (OOB rows are zero)
    int c    = tid & 63;
    int half = tid >> 6;
    float s = 0.f;
    #pragma unroll 8
    for (int j = 0; j < 64; ++j)
        s += H[(half * 64 + j) * HSTRIDE + c];
    atomicAdd(&pooled[c], s);
}

__global__ void finalize_kernel(const float* __restrict__ pooled,
                                const float* __restrict__ Wl,
                                float* __restrict__ out) {
    int c = threadIdx.x;  // 64
    float s = 0.f;
    #pragma unroll
    for (int l = 0; l < N_LAYERS; ++l)
        s += pooled[l * DIM + c] * Wl[l * DIM + c];
    #pragma unroll
    for (int off = 32; off > 0; off >>= 1)
        s += __shfl_down(s, off, 64);
    if (c == 0) {
        float logit = s / (float)N_NODES;
        out[0] = 1.f / (1.f + expf(-logit));
    }
}

extern "C" void kernel_launch(void* const* d_in, const int* in_sizes, int n_in,
                              void* d_out, int out_size, void* d_ws, size_t ws_size,
                              hipStream_t stream) {
    const float* x   = (const float*)d_in[0];
    const float* W   = (const float*)d_in[1];
    const float* Wl  = (const float*)d_in[2];
    const int*   src = (const int*)d_in[3];
    const int*   dst = (const int*)d_in[4];
    float* out = (float*)d_out;

    char* ws = (char*)d_ws;
    const size_t nodeBytes = (size_t)N_NODES * DIM * sizeof(float);   // 12.8 MB
    float* h       = (float*)(ws);
    float* agg     = (float*)(ws + nodeBytes);
    int*   csr_src = (int*)  (ws + 2 * nodeBytes);                    // 3.2 MB
    int*   rowptr  = (int*)  (ws + 2 * nodeBytes + (size_t)N_EDGES * 4);
    int*   counts  = rowptr + (N_NODES + 1);
    int*   cursor  = counts + N_NODES;
    float* pooled  = (float*)(cursor + N_NODES);                      // 5*64 floats

    hipMemsetAsync(counts, 0, N_NODES * sizeof(int), stream);
    hipMemsetAsync(cursor, 0, N_NODES * sizeof(int), stream);
    hipMemsetAsync(pooled, 0, N_LAYERS * DIM * sizeof(float), stream);

    hist_kernel<<<(N_EDGES + 255) / 256, 256, 0, stream>>>(dst, counts);
    scan_kernel<<<1, SCAN_T, 0, stream>>>(counts, rowptr);
    fill_kernel<<<(N_EDGES + 255) / 256, 256, 0, stream>>>(src, dst, rowptr, cursor, csr_src);

    const float* hcur = x;
    for (int l = 0; l < N_LAYERS; ++l) {
        gather_kernel<<<(N_NODES * 16 + 255) / 256, 256, 0, stream>>>(hcur, rowptr, csr_src, agg);
        mlp_kernel<<<(N_NODES + MLP_ROWS - 1) / MLP_ROWS, MLP_BLOCK, 0, stream>>>(
            agg, W + (size_t)l * 3 * DIM * DIM, h, pooled + l * DIM);
        hcur = h;
    }
    finalize_kernel<<<1, 64, 0, stream>>>(pooled, Wl, out);
}

// Round 3
// 625.195 us; speedup vs baseline: 6.1873x; 1.2988x over previous
//
#include <hip/hip_runtime.h>
#include <math.h>

#define N_NODES 50000
#define N_EDGES 800000
#define DIM 64
#define N_LAYERS 5

#define MLP_BLOCK 256
#define MLP_ROWS 64
#define HSTRIDE 65   // bank = (row + k) % 32 -> at most 2-way across a wave (free)

// ---------------- CSR build (per call; ws is re-poisoned every launch) ----------------

__global__ __launch_bounds__(256) void hist_kernel(const int* __restrict__ dst,
                                                   int* __restrict__ counts) {
    int e = blockIdx.x * 256 + threadIdx.x;
    if (e < N_EDGES) atomicAdd(&counts[dst[e]], 1);
}

#define SCAN_T 1024
#define CHUNK ((N_NODES + SCAN_T - 1) / SCAN_T)   // 49

__global__ __launch_bounds__(SCAN_T) void scan_kernel(const int* __restrict__ counts,
                                                      int* __restrict__ rowptr) {
    __shared__ int sums[SCAN_T];
    int tid = threadIdx.x;
    int lo = tid * CHUNK;
    int hi = min(lo + CHUNK, N_NODES);
    int s = 0;
    for (int i = lo; i < hi; ++i) s += counts[i];
    sums[tid] = s;
    __syncthreads();
    for (int off = 1; off < SCAN_T; off <<= 1) {
        int v = (tid >= off) ? sums[tid - off] : 0;
        __syncthreads();
        sums[tid] += v;
        __syncthreads();
    }
    int run = (tid > 0) ? sums[tid - 1] : 0;
    for (int i = lo; i < hi; ++i) { rowptr[i] = run; run += counts[i]; }
    if (tid == SCAN_T - 1) rowptr[N_NODES] = run;
}

__global__ __launch_bounds__(256) void fill_kernel(const int* __restrict__ src,
                                                   const int* __restrict__ dst,
                                                   const int* __restrict__ rowptr,
                                                   int* __restrict__ cursor,
                                                   int* __restrict__ csr_src) {
    int e = blockIdx.x * 256 + threadIdx.x;
    if (e >= N_EDGES) return;
    int d = dst[e];
    int pos = atomicAdd(&cursor[d], 1);
    csr_src[rowptr[d] + pos] = src[e];
}

// ---------------- aggregation: gather, no atomics ----------------
__global__ __launch_bounds__(256) void gather_kernel(const float* __restrict__ h,
                                                     const int* __restrict__ rowptr,
                                                     const int* __restrict__ csr_src,
                                                     float* __restrict__ agg) {
    int t = blockIdx.x * 256 + threadIdx.x;
    int node = t >> 4;
    if (node >= N_NODES) return;
    int g = (t & 15) << 2;
    float4 acc = *(const float4*)(h + (size_t)node * DIM + g);   // self term (eps=0)
    int e0 = rowptr[node], e1 = rowptr[node + 1];
    for (int e = e0; e < e1; ++e) {
        int s = csr_src[e];
        float4 v = *(const float4*)(h + (size_t)s * DIM + g);
        acc.x += v.x; acc.y += v.y; acc.z += v.z; acc.w += v.w;
    }
    *(float4*)(agg + (size_t)node * DIM + g) = acc;
}

// ---------------- MLP: wave q = 16-col slice, lane = row ----------------
// Per k-iter per wave: 1 s_load_dwordx16 (wave-uniform W slice) + 1 ds_read_b32 + 16 FMAs.
// 782 blocks x 4 waves = 3128 waves (~3/SIMD) hides scalar-load latency.
__global__ __launch_bounds__(MLP_BLOCK) void mlp_kernel(const float* __restrict__ agg,
                                                        const float* __restrict__ W,   // [3][64][64]
                                                        float* __restrict__ h_out,
                                                        float* __restrict__ pooled) {  // [64]
    __shared__ float H[MLP_ROWS * HSTRIDE];   // 16.6 KB
    const int tid  = threadIdx.x;
    const int row0 = blockIdx.x * MLP_ROWS;

    // fill: 64 rows x 16 float4 = 1024 float4, coalesced
    #pragma unroll
    for (int i = 0; i < 4; ++i) {
        int f4 = tid + i * MLP_BLOCK;
        int r  = f4 >> 4;
        int c  = (f4 & 15) << 2;
        int grow = row0 + r;
        float4 v = make_float4(0.f, 0.f, 0.f, 0.f);
        if (grow < N_NODES) v = *(const float4*)(agg + (size_t)grow * DIM + c);
        *(float4*)&H[r * HSTRIDE + c] = v;
    }
    __syncthreads();

    const int row = tid & 63;
    const int q   = __builtin_amdgcn_readfirstlane(tid >> 6);   // wave-uniform slice id
    const float* hrow = &H[row * HSTRIDE];

    for (int p = 0; p < 3; ++p) {
        const float* Wq = W + p * DIM * DIM + q * 16;   // SGPR base -> s_load per k
        float4 acc0 = make_float4(0.f, 0.f, 0.f, 0.f);
        float4 acc1 = make_float4(0.f, 0.f, 0.f, 0.f);
        float4 acc2 = make_float4(0.f, 0.f, 0.f, 0.f);
        float4 acc3 = make_float4(0.f, 0.f, 0.f, 0.f);
        #pragma unroll 8
        for (int k = 0; k < DIM; ++k) {
            float hk = hrow[k];                    // ds_read_b32, conflict-free
            const float* wr = Wq + k * DIM;        // wave-uniform
            float4 w0 = *(const float4*)(wr + 0);
            float4 w1 = *(const float4*)(wr + 4);
            float4 w2 = *(const float4*)(wr + 8);
            float4 w3 = *(const float4*)(wr + 12);
            acc0.x = fmaf(hk, w0.x, acc0.x); acc0.y = fmaf(hk, w0.y, acc0.y);
            acc0.z = fmaf(hk, w0.z, acc0.z); acc0.w = fmaf(hk, w0.w, acc0.w);
            acc1.x = fmaf(hk, w1.x, acc1.x); acc1.y = fmaf(hk, w1.y, acc1.y);
            acc1.z = fmaf(hk, w1.z, acc1.z); acc1.w = fmaf(hk, w1.w, acc1.w);
            acc2.x = fmaf(hk, w2.x, acc2.x); acc2.y = fmaf(hk, w2.y, acc2.y);
            acc2.z = fmaf(hk, w2.z, acc2.z); acc2.w = fmaf(hk, w2.w, acc2.w);
            acc3.x = fmaf(hk, w3.x, acc3.x); acc3.y = fmaf(hk, w3.y, acc3.y);
            acc3.z = fmaf(hk, w3.z, acc3.z); acc3.w = fmaf(hk, w3.w, acc3.w);
        }
        __syncthreads();   // everyone done READING H before slices are overwritten
        float* hw = &H[row * HSTRIDE + q * 16];
        acc0.x = fmaxf(acc0.x, 0.f); acc0.y = fmaxf(acc0.y, 0.f);
        acc0.z = fmaxf(acc0.z, 0.f); acc0.w = fmaxf(acc0.w, 0.f);
        acc1.x = fmaxf(acc1.x, 0.f); acc1.y = fmaxf(acc1.y, 0.f);
        acc1.z = fmaxf(acc1.z, 0.f); acc1.w = fmaxf(acc1.w, 0.f);
        acc2.x = fmaxf(acc2.x, 0.f); acc2.y = fmaxf(acc2.y, 0.f);
        acc2.z = fmaxf(acc2.z, 0.f); acc2.w = fmaxf(acc2.w, 0.f);
        acc3.x = fmaxf(acc3.x, 0.f); acc3.y = fmaxf(acc3.y, 0.f);
        acc3.z = fmaxf(acc3.z, 0.f); acc3.w = fmaxf(acc3.w, 0.f);
        *(float4*)(hw + 0)  = acc0;
        *(float4*)(hw + 4)  = acc1;
        *(float4*)(hw + 8)  = acc2;
        *(float4*)(hw + 12) = acc3;
        __syncthreads();
    }

    // store h for next layer's gather (coalesced)
    #pragma unroll
    for (int i = 0; i < 4; ++i) {
        int f4 = tid + i * MLP_BLOCK;
        int r  = f4 >> 4;
        int c  = (f4 & 15) << 2;
        int grow = row0 + r;
        if (grow < N_NODES)
            *(float4*)(h_out + (size_t)grow * DIM + c) = *(const float4*)&H[r * HSTRIDE + c];
    }

    // global mean pool partial: 64 threads, one column each (OOB rows are zero)
    if (tid < 64) {
        float s = 0.f;
        #pragma unroll 8
        for (int r = 0; r < MLP_ROWS; ++r)
            s += H[r * HSTRIDE + tid];
        atomicAdd(&pooled[tid], s);
    }
}

__global__ void finalize_kernel(const float* __restrict__ pooled,
                                const float* __restrict__ Wl,
                                float* __restrict__ out) {
    int c = threadIdx.x;  // 64
    float s = 0.f;
    #pragma unroll
    for (int l = 0; l < N_LAYERS; ++l)
        s += pooled[l * DIM + c] * Wl[l * DIM + c];
    #pragma unroll
    for (int off = 32; off > 0; off >>= 1)
        s += __shfl_down(s, off, 64);
    if (c == 0) {
        float logit = s / (float)N_NODES;
        out[0] = 1.f / (1.f + expf(-logit));
    }
}

extern "C" void kernel_launch(void* const* d_in, const int* in_sizes, int n_in,
                              void* d_out, int out_size, void* d_ws, size_t ws_size,
                              hipStream_t stream) {
    const float* x   = (const float*)d_in[0];
    const float* W   = (const float*)d_in[1];
    const float* Wl  = (const float*)d_in[2];
    const int*   src = (const int*)d_in[3];
    const int*   dst = (const int*)d_in[4];
    float* out = (float*)d_out;

    char* ws = (char*)d_ws;
    const size_t nodeBytes = (size_t)N_NODES * DIM * sizeof(float);   // 12.8 MB
    float* h       = (float*)(ws);
    float* agg     = (float*)(ws + nodeBytes);
    int*   csr_src = (int*)  (ws + 2 * nodeBytes);                    // 3.2 MB
    int*   rowptr  = (int*)  (ws + 2 * nodeBytes + (size_t)N_EDGES * 4);
    int*   counts  = rowptr + (N_NODES + 1);
    int*   cursor  = counts + N_NODES;
    float* pooled  = (float*)(cursor + N_NODES);                      // 5*64 floats

    hipMemsetAsync(counts, 0, N_NODES * sizeof(int), stream);
    hipMemsetAsync(cursor, 0, N_NODES * sizeof(int), stream);
    hipMemsetAsync(pooled, 0, N_LAYERS * DIM * sizeof(float), stream);

    hist_kernel<<<(N_EDGES + 255) / 256, 256, 0, stream>>>(dst, counts);
    scan_kernel<<<1, SCAN_T, 0, stream>>>(counts, rowptr);
    fill_kernel<<<(N_EDGES + 255) / 256, 256, 0, stream>>>(src, dst, rowptr, cursor, csr_src);

    const float* hcur = x;
    for (int l = 0; l < N_LAYERS; ++l) {
        gather_kernel<<<(N_NODES * 16 + 255) / 256, 256, 0, stream>>>(hcur, rowptr, csr_src, agg);
        mlp_kernel<<<(N_NODES + MLP_ROWS - 1) / MLP_ROWS, MLP_BLOCK, 0, stream>>>(
            agg, W + (size_t)l * 3 * DIM * DIM, h, pooled + l * DIM);
        hcur = h;
    }
    finalize_kernel<<<1, 64, 0, stream>>>(pooled, Wl, out);
}

// Round 4
// 615.164 us; speedup vs baseline: 6.2882x; 1.0163x over previous
//
#include <hip/hip_runtime.h>
#include <math.h>

#define N_NODES 50000
#define N_EDGES 800000
#define DIM 64
#define N_LAYERS 5

#define MLP_BLOCK 256
#define MLP_ROWS 64
#define HSTRIDE 65   // bank = (row + k) % 32 -> at most 2-way across a wave (free)

#define SCAN_BLOCKS ((N_NODES + 255) / 256)   // 196

// ---------------- CSR build (per call; ws is re-poisoned every launch) ----------------

__global__ __launch_bounds__(256) void hist_kernel(const int* __restrict__ dst,
                                                   int* __restrict__ counts) {
    int e = blockIdx.x * 256 + threadIdx.x;
    if (e < N_EDGES) atomicAdd(&counts[dst[e]], 1);
}

// phase A: per-block exclusive scan of 256 counts; emit block sums
__global__ __launch_bounds__(256) void scan_a(const int* __restrict__ counts,
                                              int* __restrict__ rowptr,
                                              int* __restrict__ blockSums) {
    __shared__ int s[256];
    int t = threadIdx.x;
    int g = blockIdx.x * 256 + t;
    int v = (g < N_NODES) ? counts[g] : 0;
    s[t] = v;
    __syncthreads();
    #pragma unroll
    for (int off = 1; off < 256; off <<= 1) {
        int u = (t >= off) ? s[t - off] : 0;
        __syncthreads();
        s[t] += u;
        __syncthreads();
    }
    if (g < N_NODES) rowptr[g] = s[t] - v;          // exclusive within block
    if (t == 255) blockSums[blockIdx.x] = s[255];
}

// phase B: one block scans the 196 block sums (exclusive)
__global__ __launch_bounds__(256) void scan_b(const int* __restrict__ blockSums,
                                              int* __restrict__ blockOffs) {
    __shared__ int s[256];
    int t = threadIdx.x;
    int v = (t < SCAN_BLOCKS) ? blockSums[t] : 0;
    s[t] = v;
    __syncthreads();
    #pragma unroll
    for (int off = 1; off < 256; off <<= 1) {
        int u = (t >= off) ? s[t - off] : 0;
        __syncthreads();
        s[t] += u;
        __syncthreads();
    }
    if (t < SCAN_BLOCKS) blockOffs[t] = s[t] - v;   // exclusive
}

// phase C: add block offsets
__global__ __launch_bounds__(256) void scan_c(int* __restrict__ rowptr,
                                              const int* __restrict__ blockOffs) {
    int t = threadIdx.x;
    int g = blockIdx.x * 256 + t;
    if (g < N_NODES) rowptr[g] += blockOffs[blockIdx.x];
    if (g == 0) rowptr[N_NODES] = N_EDGES;
}

__global__ __launch_bounds__(256) void fill_kernel(const int* __restrict__ src,
                                                   const int* __restrict__ dst,
                                                   const int* __restrict__ rowptr,
                                                   int* __restrict__ cursor,
                                                   int* __restrict__ csr_src) {
    int e = blockIdx.x * 256 + threadIdx.x;
    if (e >= N_EDGES) return;
    int d = dst[e];
    int pos = atomicAdd(&cursor[d], 1);
    csr_src[rowptr[d] + pos] = src[e];
}

// ---------------- aggregation: one node per wave, lane = column ----------------
// Edge loop is wave-uniform (no divergence); csr_src/rowptr reads scalarize.
// Each edge = one coalesced 256B row load.
__global__ __launch_bounds__(256) void gather_kernel(const float* __restrict__ h,
                                                     const int* __restrict__ rowptr,
                                                     const int* __restrict__ csr_src,
                                                     float* __restrict__ agg) {
    int lane = threadIdx.x & 63;
    int node = __builtin_amdgcn_readfirstlane(blockIdx.x * 4 + (threadIdx.x >> 6));
    if (node >= N_NODES) return;
    float acc = h[(size_t)node * DIM + lane];        // self term (eps=0)
    int e0 = rowptr[node], e1 = rowptr[node + 1];
    for (int e = e0; e < e1; ++e) {
        int s = __builtin_amdgcn_readfirstlane(csr_src[e]);
        acc += h[(size_t)s * DIM + lane];
    }
    agg[(size_t)node * DIM + lane] = acc;
}

// ---------------- MLP: wave q = 16-col slice, lane = row ----------------
__global__ __launch_bounds__(MLP_BLOCK) void mlp_kernel(const float* __restrict__ agg,
                                                        const float* __restrict__ W,   // [3][64][64]
                                                        float* __restrict__ h_out,
                                                        float* __restrict__ pooled) {  // [64]
    __shared__ float H[MLP_ROWS * HSTRIDE];   // 16.6 KB
    const int tid  = threadIdx.x;
    const int row0 = blockIdx.x * MLP_ROWS;

    #pragma unroll
    for (int i = 0; i < 4; ++i) {
        int f4 = tid + i * MLP_BLOCK;
        int r  = f4 >> 4;
        int c  = (f4 & 15) << 2;
        int grow = row0 + r;
        float4 v = make_float4(0.f, 0.f, 0.f, 0.f);
        if (grow < N_NODES) v = *(const float4*)(agg + (size_t)grow * DIM + c);
        *(float4*)&H[r * HSTRIDE + c] = v;
    }
    __syncthreads();

    const int row = tid & 63;
    const int q   = __builtin_amdgcn_readfirstlane(tid >> 6);   // wave-uniform slice id
    const float* hrow = &H[row * HSTRIDE];

    for (int p = 0; p < 3; ++p) {
        const float* Wq = W + p * DIM * DIM + q * 16;   // wave-uniform -> s_load per k
        float4 acc0 = make_float4(0.f, 0.f, 0.f, 0.f);
        float4 acc1 = make_float4(0.f, 0.f, 0.f, 0.f);
        float4 acc2 = make_float4(0.f, 0.f, 0.f, 0.f);
        float4 acc3 = make_float4(0.f, 0.f, 0.f, 0.f);
        #pragma unroll 8
        for (int k = 0; k < DIM; ++k) {
            float hk = hrow[k];                    // ds_read_b32, conflict-free
            const float* wr = Wq + k * DIM;
            float4 w0 = *(const float4*)(wr + 0);
            float4 w1 = *(const float4*)(wr + 4);
            float4 w2 = *(const float4*)(wr + 8);
            float4 w3 = *(const float4*)(wr + 12);
            acc0.x = fmaf(hk, w0.x, acc0.x); acc0.y = fmaf(hk, w0.y, acc0.y);
            acc0.z = fmaf(hk, w0.z, acc0.z); acc0.w = fmaf(hk, w0.w, acc0.w);
            acc1.x = fmaf(hk, w1.x, acc1.x); acc1.y = fmaf(hk, w1.y, acc1.y);
            acc1.z = fmaf(hk, w1.z, acc1.z); acc1.w = fmaf(hk, w1.w, acc1.w);
            acc2.x = fmaf(hk, w2.x, acc2.x); acc2.y = fmaf(hk, w2.y, acc2.y);
            acc2.z = fmaf(hk, w2.z, acc2.z); acc2.w = fmaf(hk, w2.w, acc2.w);
            acc3.x = fmaf(hk, w3.x, acc3.x); acc3.y = fmaf(hk, w3.y, acc3.y);
            acc3.z = fmaf(hk, w3.z, acc3.z); acc3.w = fmaf(hk, w3.w, acc3.w);
        }
        __syncthreads();   // all reads of H done before overwrite
        float* hw = &H[row * HSTRIDE + q * 16];
        acc0.x = fmaxf(acc0.x, 0.f); acc0.y = fmaxf(acc0.y, 0.f);
        acc0.z = fmaxf(acc0.z, 0.f); acc0.w = fmaxf(acc0.w, 0.f);
        acc1.x = fmaxf(acc1.x, 0.f); acc1.y = fmaxf(acc1.y, 0.f);
        acc1.z = fmaxf(acc1.z, 0.f); acc1.w = fmaxf(acc1.w, 0.f);
        acc2.x = fmaxf(acc2.x, 0.f); acc2.y = fmaxf(acc2.y, 0.f);
        acc2.z = fmaxf(acc2.z, 0.f); acc2.w = fmaxf(acc2.w, 0.f);
        acc3.x = fmaxf(acc3.x, 0.f); acc3.y = fmaxf(acc3.y, 0.f);
        acc3.z = fmaxf(acc3.z, 0.f); acc3.w = fmaxf(acc3.w, 0.f);
        *(float4*)(hw + 0)  = acc0;
        *(float4*)(hw + 4)  = acc1;
        *(float4*)(hw + 8)  = acc2;
        *(float4*)(hw + 12) = acc3;
        __syncthreads();
    }

    #pragma unroll
    for (int i = 0; i < 4; ++i) {
        int f4 = tid + i * MLP_BLOCK;
        int r  = f4 >> 4;
        int c  = (f4 & 15) << 2;
        int grow = row0 + r;
        if (grow < N_NODES)
            *(float4*)(h_out + (size_t)grow * DIM + c) = *(const float4*)&H[r * HSTRIDE + c];
    }

    if (tid < 64) {
        float s = 0.f;
        #pragma unroll 8
        for (int r = 0; r < MLP_ROWS; ++r)
            s += H[r * HSTRIDE + tid];
        atomicAdd(&pooled[tid], s);
    }
}

__global__ void finalize_kernel(const float* __restrict__ pooled,
                                const float* __restrict__ Wl,
                                float* __restrict__ out) {
    int c = threadIdx.x;  // 64
    float s = 0.f;
    #pragma unroll
    for (int l = 0; l < N_LAYERS; ++l)
        s += pooled[l * DIM + c] * Wl[l * DIM + c];
    #pragma unroll
    for (int off = 32; off > 0; off >>= 1)
        s += __shfl_down(s, off, 64);
    if (c == 0) {
        float logit = s / (float)N_NODES;
        out[0] = 1.f / (1.f + expf(-logit));
    }
}

extern "C" void kernel_launch(void* const* d_in, const int* in_sizes, int n_in,
                              void* d_out, int out_size, void* d_ws, size_t ws_size,
                              hipStream_t stream) {
    const float* x   = (const float*)d_in[0];
    const float* W   = (const float*)d_in[1];
    const float* Wl  = (const float*)d_in[2];
    const int*   src = (const int*)d_in[3];
    const int*   dst = (const int*)d_in[4];
    float* out = (float*)d_out;

    char* ws = (char*)d_ws;
    const size_t nodeBytes = (size_t)N_NODES * DIM * sizeof(float);   // 12.8 MB
    float* h        = (float*)(ws);
    float* agg      = (float*)(ws + nodeBytes);
    int*   csr_src  = (int*)  (ws + 2 * nodeBytes);                   // 3.2 MB
    int*   rowptr   = (int*)  (ws + 2 * nodeBytes + (size_t)N_EDGES * 4);
    int*   counts   = rowptr + (N_NODES + 1);
    int*   cursor   = counts + N_NODES;
    int*   blockSums= cursor + N_NODES;
    int*   blockOffs= blockSums + SCAN_BLOCKS;
    float* pooled   = (float*)(blockOffs + SCAN_BLOCKS);              // 5*64 floats

    hipMemsetAsync(counts, 0, N_NODES * sizeof(int), stream);
    hipMemsetAsync(cursor, 0, N_NODES * sizeof(int), stream);
    hipMemsetAsync(pooled, 0, N_LAYERS * DIM * sizeof(float), stream);

    hist_kernel<<<(N_EDGES + 255) / 256, 256, 0, stream>>>(dst, counts);
    scan_a<<<SCAN_BLOCKS, 256, 0, stream>>>(counts, rowptr, blockSums);
    scan_b<<<1, 256, 0, stream>>>(blockSums, blockOffs);
    scan_c<<<SCAN_BLOCKS, 256, 0, stream>>>(rowptr, blockOffs);
    fill_kernel<<<(N_EDGES + 255) / 256, 256, 0, stream>>>(src, dst, rowptr, cursor, csr_src);

    const float* hcur = x;
    for (int l = 0; l < N_LAYERS; ++l) {
        gather_kernel<<<(N_NODES + 3) / 4, 256, 0, stream>>>(hcur, rowptr, csr_src, agg);
        mlp_kernel<<<(N_NODES + MLP_ROWS - 1) / MLP_ROWS, MLP_BLOCK, 0, stream>>>(
            agg, W + (size_t)l * 3 * DIM * DIM, h, pooled + l * DIM);
        hcur = h;
    }
    finalize_kernel<<<1, 64, 0, stream>>>(pooled, Wl, out);
}

// Round 5
// 519.878 us; speedup vs baseline: 7.4408x; 1.1833x over previous
//
#include <hip/hip_runtime.h>
#include <math.h>

#define N_NODES 50000
#define N_EDGES 800000
#define DIM 64
#define N_LAYERS 5

#define MLP_BLOCK 256
#define MLP_ROWS 64
#define HSTRIDE 65   // bank = (row + k) % 32 -> at most 2-way across a wave (free)

#define SCAN_BLOCKS ((N_NODES + 255) / 256)   // 196

// ---------------- CSR build (per call; ws is re-poisoned every launch) ----------------

__global__ __launch_bounds__(256) void hist_kernel(const int* __restrict__ dst,
                                                   int* __restrict__ counts) {
    int e = blockIdx.x * 256 + threadIdx.x;
    if (e < N_EDGES) atomicAdd(&counts[dst[e]], 1);
}

__global__ __launch_bounds__(256) void scan_a(const int* __restrict__ counts,
                                              int* __restrict__ rowptr,
                                              int* __restrict__ blockSums) {
    __shared__ int s[256];
    int t = threadIdx.x;
    int g = blockIdx.x * 256 + t;
    int v = (g < N_NODES) ? counts[g] : 0;
    s[t] = v;
    __syncthreads();
    #pragma unroll
    for (int off = 1; off < 256; off <<= 1) {
        int u = (t >= off) ? s[t - off] : 0;
        __syncthreads();
        s[t] += u;
        __syncthreads();
    }
    if (g < N_NODES) rowptr[g] = s[t] - v;
    if (t == 255) blockSums[blockIdx.x] = s[255];
}

__global__ __launch_bounds__(256) void scan_b(const int* __restrict__ blockSums,
                                              int* __restrict__ blockOffs) {
    __shared__ int s[256];
    int t = threadIdx.x;
    int v = (t < SCAN_BLOCKS) ? blockSums[t] : 0;
    s[t] = v;
    __syncthreads();
    #pragma unroll
    for (int off = 1; off < 256; off <<= 1) {
        int u = (t >= off) ? s[t - off] : 0;
        __syncthreads();
        s[t] += u;
        __syncthreads();
    }
    if (t < SCAN_BLOCKS) blockOffs[t] = s[t] - v;
}

__global__ __launch_bounds__(256) void scan_c(int* __restrict__ rowptr,
                                              const int* __restrict__ blockOffs) {
    int t = threadIdx.x;
    int g = blockIdx.x * 256 + t;
    if (g < N_NODES) rowptr[g] += blockOffs[blockIdx.x];
    if (g == 0) rowptr[N_NODES] = N_EDGES;
}

__global__ __launch_bounds__(256) void fill_kernel(const int* __restrict__ src,
                                                   const int* __restrict__ dst,
                                                   const int* __restrict__ rowptr,
                                                   int* __restrict__ cursor,
                                                   int* __restrict__ csr_src) {
    int e = blockIdx.x * 256 + threadIdx.x;
    if (e >= N_EDGES) return;
    int d = dst[e];
    int pos = atomicAdd(&cursor[d], 1);
    csr_src[rowptr[d] + pos] = src[e];
}

// ---------------- aggregation: one node per wave, 4 edge slots in flight ----------------
// Wave = 4 x 16-lane groups; group g walks edges e0+g, e0+g+4, ... with a float4/lane
// (full 256B row per group). Manual 2x unroll -> up to 8 independent row loads in
// flight per wave. Final 4-way merge via shfl_xor butterfly.
__global__ __launch_bounds__(256) void gather_kernel(const float* __restrict__ h,
                                                     const int* __restrict__ rowptr,
                                                     const int* __restrict__ csr_src,
                                                     float* __restrict__ agg) {
    const int lane = threadIdx.x & 63;
    const int node = __builtin_amdgcn_readfirstlane(blockIdx.x * 4 + (threadIdx.x >> 6));
    const int g    = lane >> 4;          // edge slot 0..3
    const int c    = (lane & 15) << 2;   // column group

    float4 acc = make_float4(0.f, 0.f, 0.f, 0.f);
    if (g == 0) acc = *(const float4*)(h + (size_t)node * DIM + c);   // self term (eps=0)

    const int e0 = rowptr[node], e1 = rowptr[node + 1];
    int e = e0 + g;
    // 2 edges per group in flight
    for (; e + 4 < e1; e += 8) {
        int s0 = csr_src[e];
        int s1 = csr_src[e + 4];
        float4 v0 = *(const float4*)(h + (size_t)s0 * DIM + c);
        float4 v1 = *(const float4*)(h + (size_t)s1 * DIM + c);
        acc.x += v0.x + v1.x; acc.y += v0.y + v1.y;
        acc.z += v0.z + v1.z; acc.w += v0.w + v1.w;
    }
    if (e < e1) {
        int s0 = csr_src[e];
        float4 v0 = *(const float4*)(h + (size_t)s0 * DIM + c);
        acc.x += v0.x; acc.y += v0.y; acc.z += v0.z; acc.w += v0.w;
    }

    // merge the 4 group partials (columns align across groups: lane^16, lane^32)
    acc.x += __shfl_xor(acc.x, 16, 64);
    acc.y += __shfl_xor(acc.y, 16, 64);
    acc.z += __shfl_xor(acc.z, 16, 64);
    acc.w += __shfl_xor(acc.w, 16, 64);
    acc.x += __shfl_xor(acc.x, 32, 64);
    acc.y += __shfl_xor(acc.y, 32, 64);
    acc.z += __shfl_xor(acc.z, 32, 64);
    acc.w += __shfl_xor(acc.w, 32, 64);

    if (g == 0)
        *(float4*)(agg + (size_t)node * DIM + c) = acc;
}

// ---------------- MLP: wave q = 16-col slice, lane = row (unchanged from R3) ----------------
__global__ __launch_bounds__(MLP_BLOCK) void mlp_kernel(const float* __restrict__ agg,
                                                        const float* __restrict__ W,   // [3][64][64]
                                                        float* __restrict__ h_out,
                                                        float* __restrict__ pooled) {  // [64]
    __shared__ float H[MLP_ROWS * HSTRIDE];   // 16.6 KB
    const int tid  = threadIdx.x;
    const int row0 = blockIdx.x * MLP_ROWS;

    #pragma unroll
    for (int i = 0; i < 4; ++i) {
        int f4 = tid + i * MLP_BLOCK;
        int r  = f4 >> 4;
        int c  = (f4 & 15) << 2;
        int grow = row0 + r;
        float4 v = make_float4(0.f, 0.f, 0.f, 0.f);
        if (grow < N_NODES) v = *(const float4*)(agg + (size_t)grow * DIM + c);
        *(float4*)&H[r * HSTRIDE + c] = v;
    }
    __syncthreads();

    const int row = tid & 63;
    const int q   = __builtin_amdgcn_readfirstlane(tid >> 6);
    const float* hrow = &H[row * HSTRIDE];

    for (int p = 0; p < 3; ++p) {
        const float* Wq = W + p * DIM * DIM + q * 16;
        float4 acc0 = make_float4(0.f, 0.f, 0.f, 0.f);
        float4 acc1 = make_float4(0.f, 0.f, 0.f, 0.f);
        float4 acc2 = make_float4(0.f, 0.f, 0.f, 0.f);
        float4 acc3 = make_float4(0.f, 0.f, 0.f, 0.f);
        #pragma unroll 8
        for (int k = 0; k < DIM; ++k) {
            float hk = hrow[k];
            const float* wr = Wq + k * DIM;
            float4 w0 = *(const float4*)(wr + 0);
            float4 w1 = *(const float4*)(wr + 4);
            float4 w2 = *(const float4*)(wr + 8);
            float4 w3 = *(const float4*)(wr + 12);
            acc0.x = fmaf(hk, w0.x, acc0.x); acc0.y = fmaf(hk, w0.y, acc0.y);
            acc0.z = fmaf(hk, w0.z, acc0.z); acc0.w = fmaf(hk, w0.w, acc0.w);
            acc1.x = fmaf(hk, w1.x, acc1.x); acc1.y = fmaf(hk, w1.y, acc1.y);
            acc1.z = fmaf(hk, w1.z, acc1.z); acc1.w = fmaf(hk, w1.w, acc1.w);
            acc2.x = fmaf(hk, w2.x, acc2.x); acc2.y = fmaf(hk, w2.y, acc2.y);
            acc2.z = fmaf(hk, w2.z, acc2.z); acc2.w = fmaf(hk, w2.w, acc2.w);
            acc3.x = fmaf(hk, w3.x, acc3.x); acc3.y = fmaf(hk, w3.y, acc3.y);
            acc3.z = fmaf(hk, w3.z, acc3.z); acc3.w = fmaf(hk, w3.w, acc3.w);
        }
        __syncthreads();
        float* hw = &H[row * HSTRIDE + q * 16];
        acc0.x = fmaxf(acc0.x, 0.f); acc0.y = fmaxf(acc0.y, 0.f);
        acc0.z = fmaxf(acc0.z, 0.f); acc0.w = fmaxf(acc0.w, 0.f);
        acc1.x = fmaxf(acc1.x, 0.f); acc1.y = fmaxf(acc1.y, 0.f);
        acc1.z = fmaxf(acc1.z, 0.f); acc1.w = fmaxf(acc1.w, 0.f);
        acc2.x = fmaxf(acc2.x, 0.f); acc2.y = fmaxf(acc2.y, 0.f);
        acc2.z = fmaxf(acc2.z, 0.f); acc2.w = fmaxf(acc2.w, 0.f);
        acc3.x = fmaxf(acc3.x, 0.f); acc3.y = fmaxf(acc3.y, 0.f);
        acc3.z = fmaxf(acc3.z, 0.f); acc3.w = fmaxf(acc3.w, 0.f);
        *(float4*)(hw + 0)  = acc0;
        *(float4*)(hw + 4)  = acc1;
        *(float4*)(hw + 8)  = acc2;
        *(float4*)(hw + 12) = acc3;
        __syncthreads();
    }

    #pragma unroll
    for (int i = 0; i < 4; ++i) {
        int f4 = tid + i * MLP_BLOCK;
        int r  = f4 >> 4;
        int c  = (f4 & 15) << 2;
        int grow = row0 + r;
        if (grow < N_NODES)
            *(float4*)(h_out + (size_t)grow * DIM + c) = *(const float4*)&H[r * HSTRIDE + c];
    }

    if (tid < 64) {
        float s = 0.f;
        #pragma unroll 8
        for (int r = 0; r < MLP_ROWS; ++r)
            s += H[r * HSTRIDE + tid];
        atomicAdd(&pooled[tid], s);
    }
}

__global__ void finalize_kernel(const float* __restrict__ pooled,
                                const float* __restrict__ Wl,
                                float* __restrict__ out) {
    int c = threadIdx.x;  // 64
    float s = 0.f;
    #pragma unroll
    for (int l = 0; l < N_LAYERS; ++l)
        s += pooled[l * DIM + c] * Wl[l * DIM + c];
    #pragma unroll
    for (int off = 32; off > 0; off >>= 1)
        s += __shfl_down(s, off, 64);
    if (c == 0) {
        float logit = s / (float)N_NODES;
        out[0] = 1.f / (1.f + expf(-logit));
    }
}

extern "C" void kernel_launch(void* const* d_in, const int* in_sizes, int n_in,
                              void* d_out, int out_size, void* d_ws, size_t ws_size,
                              hipStream_t stream) {
    const float* x   = (const float*)d_in[0];
    const float* W   = (const float*)d_in[1];
    const float* Wl  = (const float*)d_in[2];
    const int*   src = (const int*)d_in[3];
    const int*   dst = (const int*)d_in[4];
    float* out = (float*)d_out;

    char* ws = (char*)d_ws;
    const size_t nodeBytes = (size_t)N_NODES * DIM * sizeof(float);   // 12.8 MB
    float* h        = (float*)(ws);
    float* agg      = (float*)(ws + nodeBytes);
    int*   csr_src  = (int*)  (ws + 2 * nodeBytes);                   // 3.2 MB
    int*   rowptr   = (int*)  (ws + 2 * nodeBytes + (size_t)N_EDGES * 4);
    int*   counts   = rowptr + (N_NODES + 1);
    int*   cursor   = counts + N_NODES;
    int*   blockSums= cursor + N_NODES;
    int*   blockOffs= blockSums + SCAN_BLOCKS;
    float* pooled   = (float*)(blockOffs + SCAN_BLOCKS);              // 5*64 floats

    hipMemsetAsync(counts, 0, N_NODES * sizeof(int), stream);
    hipMemsetAsync(cursor, 0, N_NODES * sizeof(int), stream);
    hipMemsetAsync(pooled, 0, N_LAYERS * DIM * sizeof(float), stream);

    hist_kernel<<<(N_EDGES + 255) / 256, 256, 0, stream>>>(dst, counts);
    scan_a<<<SCAN_BLOCKS, 256, 0, stream>>>(counts, rowptr, blockSums);
    scan_b<<<1, 256, 0, stream>>>(blockSums, blockOffs);
    scan_c<<<SCAN_BLOCKS, 256, 0, stream>>>(rowptr, blockOffs);
    fill_kernel<<<(N_EDGES + 255) / 256, 256, 0, stream>>>(src, dst, rowptr, cursor, csr_src);

    const float* hcur = x;
    for (int l = 0; l < N_LAYERS; ++l) {
        gather_kernel<<<N_NODES / 4, 256, 0, stream>>>(hcur, rowptr, csr_src, agg);
        mlp_kernel<<<(N_NODES + MLP_ROWS - 1) / MLP_ROWS, MLP_BLOCK, 0, stream>>>(
            agg, W + (size_t)l * 3 * DIM * DIM, h, pooled + l * DIM);
        hcur = h;
    }
    finalize_kernel<<<1, 64, 0, stream>>>(pooled, Wl, out);
}